// Round 1
// 284.679 us; speedup vs baseline: 1.1757x; 1.1757x over previous
//
#include <hip/hip_runtime.h>
#include <math.h>

#define L_SEQ 1024
#define DMODEL 512
#define NHEAD 8
#define NB 2

typedef __attribute__((ext_vector_type(8))) short bf8;
typedef __attribute__((ext_vector_type(4))) float f4;

__device__ __forceinline__ short f2bf(float f) {
    unsigned u = __float_as_uint(f);
    unsigned r = u + 0x7FFF + ((u >> 16) & 1);   // round-to-nearest-even
    return (short)(r >> 16);
}

// ---------------------------------------------------------------------------
// fp32 -> bf16 cast, vectorized
// ---------------------------------------------------------------------------
__global__ __launch_bounds__(256) void cast_bf16_kernel(
    const float* __restrict__ src, short* __restrict__ dst, int n4)
{
    int i = blockIdx.x * 256 + threadIdx.x;
    if (i < n4) {
        float4 f = ((const float4*)src)[i];
        short4 o;
        o.x = f2bf(f.x); o.y = f2bf(f.y); o.z = f2bf(f.z); o.w = f2bf(f.w);
        ((short4*)dst)[i] = o;
    }
}

// ---------------------------------------------------------------------------
// 512x512 fp32 W[k][n] -> bf16 Wt[n][k], 4 matrices via blockIdx.z
// ---------------------------------------------------------------------------
__global__ __launch_bounds__(256) void transpose_cast_kernel(
    const float* __restrict__ s0, const float* __restrict__ s1,
    const float* __restrict__ s2, const float* __restrict__ s3,
    short* __restrict__ d0, short* __restrict__ d1,
    short* __restrict__ d2, short* __restrict__ d3)
{
    const float* src; short* dst;
    switch (blockIdx.z) {
        case 0: src = s0; dst = d0; break;
        case 1: src = s1; dst = d1; break;
        case 2: src = s2; dst = d2; break;
        default: src = s3; dst = d3; break;
    }
    __shared__ float tile[32][33];
    const int tx = threadIdx.x, ty = threadIdx.y;
    const int x0 = blockIdx.x * 32, y0 = blockIdx.y * 32;
#pragma unroll
    for (int j = 0; j < 32; j += 8)
        tile[ty + j][tx] = src[(size_t)(y0 + ty + j) * 512 + x0 + tx];
    __syncthreads();
#pragma unroll
    for (int j = 0; j < 32; j += 8)
        dst[(size_t)(x0 + ty + j) * 512 + y0 + tx] = f2bf(tile[tx][ty + j]);
}

// ---------------------------------------------------------------------------
// MFMA GEMM: C[m,n] = sum_k A[m,k]*Bt[n,k] + bias[n]
// ---------------------------------------------------------------------------
template<int MODE>
__global__ __launch_bounds__(256) void gemm_mfma_kernel(
    const short* __restrict__ A, const short* __restrict__ Bt,
    const float* __restrict__ bias, void* __restrict__ Cout)
{
    const int w = threadIdx.x >> 6, lane = threadIdx.x & 63;
    const int lr = lane & 15, lq = lane >> 4;
    const int m_base = blockIdx.y * 64 + w * 16;
    const int n_base = blockIdx.x * 64;

    f4 acc[4];
    const f4 zero = {0.f, 0.f, 0.f, 0.f};
#pragma unroll
    for (int nf = 0; nf < 4; ++nf) acc[nf] = zero;

    for (int k0 = 0; k0 < 512; k0 += 32) {
        bf8 a = *(const bf8*)(A + (size_t)(m_base + lr) * 512 + k0 + lq * 8);
#pragma unroll
        for (int nf = 0; nf < 4; ++nf) {
            bf8 b = *(const bf8*)(Bt + (size_t)(n_base + nf * 16 + lr) * 512 + k0 + lq * 8);
            acc[nf] = __builtin_amdgcn_mfma_f32_16x16x32_bf16(a, b, acc[nf], 0, 0, 0);
        }
    }

#pragma unroll
    for (int nf = 0; nf < 4; ++nf) {
        const int n = n_base + nf * 16 + lr;
        const float bv = bias[n];
        const int mrow = m_base + lq * 4;
#pragma unroll
        for (int r = 0; r < 4; ++r) {
            const float val = acc[nf][r] + bv;
            const int m = mrow + r;
            if (MODE == 0) {
                ((short*)Cout)[(size_t)m * 512 + n] = f2bf(val);
            } else if (MODE == 1) {
                const int bb = m >> 10, l = m & 1023;
                ((short*)Cout)[((size_t)bb * 512 + n) * 1024 + l] = f2bf(val);
            } else {
                ((float*)Cout)[(size_t)m * 512 + n] = val;
            }
        }
    }
}

// ---------------------------------------------------------------------------
// Scores GEMM: per z=h*2+b, S[l,m] = sum_d qh[b,l,h*64+d]*kh[b,m,h*64+d]
// ---------------------------------------------------------------------------
__global__ __launch_bounds__(256) void scores_mfma_kernel(
    const short* __restrict__ qh, const short* __restrict__ kh,
    float* __restrict__ sc)
{
    const int z = blockIdx.z, h = z >> 1, b = z & 1;
    const int w = threadIdx.x >> 6, lane = threadIdx.x & 63;
    const int wr = w >> 1, wc = w & 1;
    const int lr = lane & 15, lq = lane >> 4;
    const int l0 = blockIdx.y * 128 + wr * 64;
    const int m0 = blockIdx.x * 128 + wc * 64;
    const int colb = h * 64 + lq * 8;
    const size_t base = (size_t)b * L_SEQ * DMODEL;

    bf8 afr[4][2], bfr[4][2];
#pragma unroll
    for (int i = 0; i < 4; ++i)
#pragma unroll
        for (int kk = 0; kk < 2; ++kk) {
            afr[i][kk] = *(const bf8*)(qh + base + (size_t)(l0 + i * 16 + lr) * 512 + colb + kk * 32);
            bfr[i][kk] = *(const bf8*)(kh + base + (size_t)(m0 + i * 16 + lr) * 512 + colb + kk * 32);
        }

    f4 acc[4][4];
    const f4 zero = {0.f, 0.f, 0.f, 0.f};
#pragma unroll
    for (int mt = 0; mt < 4; ++mt)
#pragma unroll
        for (int nt = 0; nt < 4; ++nt) acc[mt][nt] = zero;

#pragma unroll
    for (int kk = 0; kk < 2; ++kk)
#pragma unroll
        for (int mt = 0; mt < 4; ++mt)
#pragma unroll
            for (int nt = 0; nt < 4; ++nt)
                acc[mt][nt] = __builtin_amdgcn_mfma_f32_16x16x32_bf16(
                    afr[mt][kk], bfr[nt][kk], acc[mt][nt], 0, 0, 0);

    float* out = sc + (size_t)z * L_SEQ * L_SEQ;
#pragma unroll
    for (int mt = 0; mt < 4; ++mt)
#pragma unroll
        for (int nt = 0; nt < 4; ++nt)
#pragma unroll
            for (int r = 0; r < 4; ++r)
                out[(size_t)(l0 + mt * 16 + lq * 4 + r) * 1024 + m0 + nt * 16 + lr] = acc[mt][nt][r];
}

// ---------------------------------------------------------------------------
// bias + mask + softmax, one block per (b,l), all 8 heads; in-place on attn.
// Register-resident scores: thread t owns columns 4t..4t+3 for all 8 heads.
// LDS = embs (10 KB) + 2x [4][8] reduce scratch. No s[][] row buffer.
// ---------------------------------------------------------------------------
__global__ __launch_bounds__(256, 4) void bias_softmax_kernel(
    float* __restrict__ attn,
    const int* __restrict__ mask,
    const int* __restrict__ tf1, const int* __restrict__ tf2,
    const int* __restrict__ tf3, const int* __restrict__ tf4,
    const int* __restrict__ tf5,
    const float* __restrict__ emb1, const float* __restrict__ emb2,
    const float* __restrict__ emb3, const float* __restrict__ emb4,
    const float* __restrict__ emb5)
{
    const int l = blockIdx.x, b = blockIdx.y, t = threadIdx.x;
    __shared__ float embs[5][NHEAD][64];     // bank = idx%32 -> random-idx gather ~conflict-free
    __shared__ float redmx[4][NHEAD];
    __shared__ float redsm[4][NHEAD];

    {
        const float* es[5] = {emb1, emb2, emb3, emb4, emb5};
#pragma unroll
        for (int it = 0; it < 10; ++it) {
            const int i = it * 256 + t;          // i>>9 is compile-time-uniform per it
            const int j = it >> 1;               // = i >> 9
            const int rem = i & 511;
            const int h = rem >> 6, idx = rem & 63;
            embs[j][h][idx] = es[j][idx * NHEAD + h];
        }
    }
    __syncthreads();

    const size_t rowbase = ((size_t)(b * L_SEQ + l)) * L_SEQ + (size_t)(t * 4);
    const int4 mk  = *(const int4*)(mask + rowbase);
    const int4 i1v = *(const int4*)(tf1 + rowbase);
    const int4 i2v = *(const int4*)(tf2 + rowbase);
    const int4 i3v = *(const int4*)(tf3 + rowbase);
    const int4 i4v = *(const int4*)(tf4 + rowbase);
    const int4 i5v = *(const int4*)(tf5 + rowbase);

    f4 av[NHEAD];
#pragma unroll
    for (int h = 0; h < NHEAD; ++h)
        av[h] = *(const f4*)(attn + ((size_t)(h * NB + b) * L_SEQ + l) * L_SEQ + t * 4);

    // fold bias + mask + 1/temp into registers, branchless on tf1 sign
#define BIAS_FOLD(MI, I1, I2, I3, I4, I5, MK)                                   \
    {                                                                           \
        const float tfm = ((I1) >= 0) ? 1.0f : 0.0f;                            \
        const int c1 = ((I1) >= 0) ? (I1) : 0;                                  \
        _Pragma("unroll")                                                       \
        for (int h = 0; h < NHEAD; ++h) {                                       \
            const float bsum = embs[0][h][c1] + embs[1][h][I2]                  \
                             + embs[2][h][I3] + embs[3][h][I4]                  \
                             + embs[4][h][I5];                                  \
            av[h][MI] = (MK) ? -INFINITY                                        \
                             : (av[h][MI] + bsum * tfm) * 0.125f;               \
        }                                                                       \
    }

    BIAS_FOLD(0, i1v.x, i2v.x, i3v.x, i4v.x, i5v.x, mk.x)
    BIAS_FOLD(1, i1v.y, i2v.y, i3v.y, i4v.y, i5v.y, mk.y)
    BIAS_FOLD(2, i1v.z, i2v.z, i3v.z, i4v.z, i5v.z, mk.z)
    BIAS_FOLD(3, i1v.w, i2v.w, i3v.w, i4v.w, i5v.w, mk.w)
#undef BIAS_FOLD

    const int wid = t >> 6, lane = t & 63;

    // per-head row max: 4 local -> 64-lane butterfly -> cross-wave via LDS
    float mx[NHEAD];
#pragma unroll
    for (int h = 0; h < NHEAD; ++h)
        mx[h] = fmaxf(fmaxf(av[h][0], av[h][1]), fmaxf(av[h][2], av[h][3]));
#pragma unroll
    for (int h = 0; h < NHEAD; ++h) {
#pragma unroll
        for (int off = 1; off < 64; off <<= 1)
            mx[h] = fmaxf(mx[h], __shfl_xor(mx[h], off));
    }
    if (lane == 0) {
#pragma unroll
        for (int h = 0; h < NHEAD; ++h) redmx[wid][h] = mx[h];
    }
    __syncthreads();
#pragma unroll
    for (int h = 0; h < NHEAD; ++h)
        mx[h] = fmaxf(fmaxf(redmx[0][h], redmx[1][h]),
                      fmaxf(redmx[2][h], redmx[3][h]));

    // exp + per-head sum
    float sm[NHEAD];
#pragma unroll
    for (int h = 0; h < NHEAD; ++h) {
        f4 e;
        e[0] = __expf(av[h][0] - mx[h]);
        e[1] = __expf(av[h][1] - mx[h]);
        e[2] = __expf(av[h][2] - mx[h]);
        e[3] = __expf(av[h][3] - mx[h]);
        av[h] = e;
        sm[h] = (e[0] + e[1]) + (e[2] + e[3]);
    }
#pragma unroll
    for (int h = 0; h < NHEAD; ++h) {
#pragma unroll
        for (int off = 1; off < 64; off <<= 1)
            sm[h] += __shfl_xor(sm[h], off);
    }
    if (lane == 0) {
#pragma unroll
        for (int h = 0; h < NHEAD; ++h) redsm[wid][h] = sm[h];
    }
    __syncthreads();

#pragma unroll
    for (int h = 0; h < NHEAD; ++h) {
        const float tot = (redsm[0][h] + redsm[1][h]) + (redsm[2][h] + redsm[3][h]);
        const float inv = 1.0f / tot;
        f4 o = av[h] * inv;
        *(f4*)(attn + ((size_t)(h * NB + b) * L_SEQ + l) * L_SEQ + t * 4) = o;
    }
}

// ---------------------------------------------------------------------------
// AV GEMM: per z=h*2+b, pv[b,l,h*64+d] = sum_m attn[z,l,m] * vht[b,h*64+d,m]
// ---------------------------------------------------------------------------
__global__ __launch_bounds__(256) void av_mfma_kernel(
    const float* __restrict__ attn, const short* __restrict__ vht,
    short* __restrict__ pv)
{
    const int z = blockIdx.y, h = z >> 1, b = z & 1;
    const int w = threadIdx.x >> 6, lane = threadIdx.x & 63;
    const int lr = lane & 15, lq = lane >> 4;
    const int l0 = blockIdx.x * 128 + w * 32;
    const float* Ab = attn + (size_t)z * L_SEQ * L_SEQ;
    const short* Bb = vht + ((size_t)b * 512 + h * 64) * 1024;

    f4 acc[2][4];
    const f4 zero = {0.f, 0.f, 0.f, 0.f};
#pragma unroll
    for (int mt = 0; mt < 2; ++mt)
#pragma unroll
        for (int nt = 0; nt < 4; ++nt) acc[mt][nt] = zero;

    for (int k0 = 0; k0 < L_SEQ; k0 += 32) {
        bf8 a[2];
#pragma unroll
        for (int mt = 0; mt < 2; ++mt) {
            const float* p = Ab + (size_t)(l0 + mt * 16 + lr) * 1024 + k0 + lq * 8;
            float4 f0 = *(const float4*)p;
            float4 f1 = *(const float4*)(p + 4);
            bf8 tv;
            tv[0] = f2bf(f0.x); tv[1] = f2bf(f0.y); tv[2] = f2bf(f0.z); tv[3] = f2bf(f0.w);
            tv[4] = f2bf(f1.x); tv[5] = f2bf(f1.y); tv[6] = f2bf(f1.z); tv[7] = f2bf(f1.w);
            a[mt] = tv;
        }
#pragma unroll
        for (int nt = 0; nt < 4; ++nt) {
            bf8 bv = *(const bf8*)(Bb + (size_t)(nt * 16 + lr) * 1024 + k0 + lq * 8);
            acc[0][nt] = __builtin_amdgcn_mfma_f32_16x16x32_bf16(a[0], bv, acc[0][nt], 0, 0, 0);
            acc[1][nt] = __builtin_amdgcn_mfma_f32_16x16x32_bf16(a[1], bv, acc[1][nt], 0, 0, 0);
        }
    }

#pragma unroll
    for (int nt = 0; nt < 4; ++nt) {
        const int n = nt * 16 + lr;
#pragma unroll
        for (int mt = 0; mt < 2; ++mt) {
            const int rowb = l0 + mt * 16 + lq * 4;
#pragma unroll
            for (int r = 0; r < 4; ++r)
                pv[(size_t)(b * L_SEQ + rowb + r) * 512 + h * 64 + n] = f2bf(acc[mt][nt][r]);
        }
    }
}

// ---------------------------------------------------------------------------
// residual add + LayerNorm, one block per row
// ---------------------------------------------------------------------------
__global__ __launch_bounds__(256) void ln_kernel(
    const float* __restrict__ x, const float* __restrict__ res,
    const float* __restrict__ g, const float* __restrict__ bvec,
    float* __restrict__ out)
{
    const int row = blockIdx.x;
    const int t = threadIdx.x;
    float2 xv = ((const float2*)(x + (size_t)row * DMODEL))[t];
    float2 rv = ((const float2*)(res + (size_t)row * DMODEL))[t];
    const float a = xv.x + rv.x;
    const float c = xv.y + rv.y;
    float s = a + c, sq = a * a + c * c;
#pragma unroll
    for (int off = 32; off; off >>= 1) {
        s  += __shfl_down(s, off);
        sq += __shfl_down(sq, off);
    }
    __shared__ float ssum[4], ssq[4];
    __shared__ float smu, srs;
    const int wid = t >> 6, lane = t & 63;
    if (lane == 0) { ssum[wid] = s; ssq[wid] = sq; }
    __syncthreads();
    if (t == 0) {
        float ts = ssum[0] + ssum[1] + ssum[2] + ssum[3];
        float tq = ssq[0] + ssq[1] + ssq[2] + ssq[3];
        float mu = ts * (1.0f / DMODEL);
        float var = tq * (1.0f / DMODEL) - mu * mu;
        smu = mu;
        srs = rsqrtf(var + 1e-5f);
    }
    __syncthreads();
    const float mu = smu, rs = srs;
    float2 gv = ((const float2*)g)[t];
    float2 bv = ((const float2*)bvec)[t];
    float2 o;
    o.x = (a - mu) * rs * gv.x + bv.x;
    o.y = (c - mu) * rs * gv.y + bv.y;
    ((float2*)(out + (size_t)row * DMODEL))[t] = o;
}

extern "C" void kernel_launch(void* const* d_in, const int* in_sizes, int n_in,
                              void* d_out, int out_size, void* d_ws, size_t ws_size,
                              hipStream_t stream)
{
    const float* q    = (const float*)d_in[0];
    const float* k    = (const float*)d_in[1];
    const float* v    = (const float*)d_in[2];
    const int*   mask = (const int*)d_in[3];
    const int*   tf1  = (const int*)d_in[4];
    const int*   tf2  = (const int*)d_in[5];
    const int*   tf3  = (const int*)d_in[6];
    const int*   tf4  = (const int*)d_in[7];
    const int*   tf5  = (const int*)d_in[8];
    const float* w_q  = (const float*)d_in[9];
    const float* b_q  = (const float*)d_in[10];
    const float* w_k  = (const float*)d_in[11];
    const float* b_k  = (const float*)d_in[12];
    const float* w_v  = (const float*)d_in[13];
    const float* b_v  = (const float*)d_in[14];
    const float* emb1 = (const float*)d_in[15];
    const float* emb2 = (const float*)d_in[16];
    const float* emb3 = (const float*)d_in[17];
    const float* emb4 = (const float*)d_in[18];
    const float* emb5 = (const float*)d_in[19];
    const float* fc_w = (const float*)d_in[20];
    const float* fc_b = (const float*)d_in[21];
    const float* ln_g = (const float*)d_in[22];
    const float* ln_b = (const float*)d_in[23];

    float* out  = (float*)d_out;                       // [2048][512]
    float* attn = out + (size_t)NB * L_SEQ * DMODEL;   // [16][1024][1024]

    // ws layout (bytes): total exactly 20 MiB
    char* wsb = (char*)d_ws;
    short* qb   = (short*)(wsb + 0);                    // 2 MiB  [2048][512] bf16
    short* kb   = (short*)(wsb + (2u << 20));           // 2 MiB
    short* vb   = (short*)(wsb + (4u << 20));           // 2 MiB
    short* Wtq  = (short*)(wsb + (6u << 20));           // 0.5 MiB [512n][512k]
    short* Wtk  = (short*)(wsb + (6u << 20) + (512u << 10));
    short* Wtv  = (short*)(wsb + (7u << 20));
    short* Wtfc = (short*)(wsb + (7u << 20) + (512u << 10));
    short* qh   = (short*)(wsb + (8u << 20));           // 2 MiB [2048][512] bf16
    short* kh   = (short*)(wsb + (10u << 20));          // 2 MiB
    short* vht  = (short*)(wsb + (12u << 20));          // 2 MiB [2][512][1024] bf16
    short* pv   = (short*)(wsb + (14u << 20));          // 2 MiB [2048][512] bf16
    float* fco  = (float*)(wsb + (16u << 20));          // 4 MiB [2048][512] fp32

    const int n4 = NB * L_SEQ * DMODEL / 4;             // 262144

    cast_bf16_kernel<<<n4 / 256, 256, 0, stream>>>(q, qb, n4);
    cast_bf16_kernel<<<n4 / 256, 256, 0, stream>>>(k, kb, n4);
    cast_bf16_kernel<<<n4 / 256, 256, 0, stream>>>(v, vb, n4);

    transpose_cast_kernel<<<dim3(16, 16, 4), dim3(32, 8), 0, stream>>>(
        w_q, w_k, w_v, fc_w, Wtq, Wtk, Wtv, Wtfc);

    dim3 gproj(DMODEL / 64, NB * L_SEQ / 64);           // (8, 32)
    gemm_mfma_kernel<0><<<gproj, 256, 0, stream>>>(qb, Wtq, b_q, qh);
    gemm_mfma_kernel<0><<<gproj, 256, 0, stream>>>(kb, Wtk, b_k, kh);
    gemm_mfma_kernel<1><<<gproj, 256, 0, stream>>>(vb, Wtv, b_v, vht);

    scores_mfma_kernel<<<dim3(8, 8, 16), 256, 0, stream>>>(qh, kh, attn);

    bias_softmax_kernel<<<dim3(L_SEQ, NB), 256, 0, stream>>>(
        attn, mask, tf1, tf2, tf3, tf4, tf5, emb1, emb2, emb3, emb4, emb5);

    av_mfma_kernel<<<dim3(8, 16), 256, 0, stream>>>(attn, vht, pv);

    gemm_mfma_kernel<2><<<gproj, 256, 0, stream>>>(pv, Wtfc, fc_b, fco);

    ln_kernel<<<NB * L_SEQ, 256, 0, stream>>>(fco, q, ln_g, ln_b, out);
}

// Round 2
// 274.776 us; speedup vs baseline: 1.2181x; 1.0360x over previous
//
#include <hip/hip_runtime.h>
#include <math.h>

#define L_SEQ 1024
#define DMODEL 512
#define NHEAD 8
#define NB 2

typedef __attribute__((ext_vector_type(8))) short bf8;
typedef __attribute__((ext_vector_type(4))) float f4;

__device__ __forceinline__ short f2bf(float f) {
    unsigned u = __float_as_uint(f);
    unsigned r = u + 0x7FFF + ((u >> 16) & 1);   // round-to-nearest-even
    return (short)(r >> 16);
}

// ---------------------------------------------------------------------------
// fp32 -> bf16 cast, vectorized, 3 tensors in one launch (z = blockIdx.y)
// ---------------------------------------------------------------------------
__global__ __launch_bounds__(256) void cast3_bf16_kernel(
    const float* __restrict__ s0, const float* __restrict__ s1,
    const float* __restrict__ s2,
    short* __restrict__ d0, short* __restrict__ d1, short* __restrict__ d2,
    int n4)
{
    const float* src; short* dst;
    switch (blockIdx.y) {
        case 0: src = s0; dst = d0; break;
        case 1: src = s1; dst = d1; break;
        default: src = s2; dst = d2; break;
    }
    int i = blockIdx.x * 256 + threadIdx.x;
    if (i < n4) {
        float4 f = ((const float4*)src)[i];
        short4 o;
        o.x = f2bf(f.x); o.y = f2bf(f.y); o.z = f2bf(f.z); o.w = f2bf(f.w);
        ((short4*)dst)[i] = o;
    }
}

// ---------------------------------------------------------------------------
// 512x512 fp32 W[k][n] -> bf16 Wt[n][k], 4 matrices via blockIdx.z
// ---------------------------------------------------------------------------
__global__ __launch_bounds__(256) void transpose_cast_kernel(
    const float* __restrict__ s0, const float* __restrict__ s1,
    const float* __restrict__ s2, const float* __restrict__ s3,
    short* __restrict__ d0, short* __restrict__ d1,
    short* __restrict__ d2, short* __restrict__ d3)
{
    const float* src; short* dst;
    switch (blockIdx.z) {
        case 0: src = s0; dst = d0; break;
        case 1: src = s1; dst = d1; break;
        case 2: src = s2; dst = d2; break;
        default: src = s3; dst = d3; break;
    }
    __shared__ float tile[32][33];
    const int tx = threadIdx.x, ty = threadIdx.y;
    const int x0 = blockIdx.x * 32, y0 = blockIdx.y * 32;
#pragma unroll
    for (int j = 0; j < 32; j += 8)
        tile[ty + j][tx] = src[(size_t)(y0 + ty + j) * 512 + x0 + tx];
    __syncthreads();
#pragma unroll
    for (int j = 0; j < 32; j += 8)
        dst[(size_t)(x0 + ty + j) * 512 + y0 + tx] = f2bf(tile[tx][ty + j]);
}

// ---------------------------------------------------------------------------
// Projection GEMMs, all 3 in one launch (z = 0:q, 1:k, 2:v).
// Block = 128 thr = 2 waves; tile 32m x 32n; wave w owns rows m_base+w*16..+15,
// 32 n via 2 MFMA n-frags. grid (16, 64, 3) = 3072 blocks -> 24 waves/CU.
// z<2 writes natural bf16 [m][512]; z==2 writes vht[b][n][l] transposed.
// ---------------------------------------------------------------------------
__global__ __launch_bounds__(128) void proj_gemm_kernel(
    const short* __restrict__ qb, const short* __restrict__ kb,
    const short* __restrict__ vb,
    const short* __restrict__ Wtq, const short* __restrict__ Wtk,
    const short* __restrict__ Wtv,
    const float* __restrict__ b_q, const float* __restrict__ b_k,
    const float* __restrict__ b_v,
    short* __restrict__ qh, short* __restrict__ kh, short* __restrict__ vht)
{
    const int z = blockIdx.z;
    const short* A    = (z == 0) ? qb  : (z == 1) ? kb  : vb;
    const short* Bt   = (z == 0) ? Wtq : (z == 1) ? Wtk : Wtv;
    const float* bias = (z == 0) ? b_q : (z == 1) ? b_k : b_v;

    const int w = threadIdx.x >> 6, lane = threadIdx.x & 63;
    const int lr = lane & 15, lq = lane >> 4;
    const int m_base = blockIdx.y * 32 + w * 16;
    const int n_base = blockIdx.x * 32;

    f4 acc[2];
    const f4 zero = {0.f, 0.f, 0.f, 0.f};
    acc[0] = zero; acc[1] = zero;

    for (int k0 = 0; k0 < 512; k0 += 32) {
        bf8 a = *(const bf8*)(A + (size_t)(m_base + lr) * 512 + k0 + lq * 8);
#pragma unroll
        for (int nf = 0; nf < 2; ++nf) {
            bf8 b = *(const bf8*)(Bt + (size_t)(n_base + nf * 16 + lr) * 512 + k0 + lq * 8);
            acc[nf] = __builtin_amdgcn_mfma_f32_16x16x32_bf16(a, b, acc[nf], 0, 0, 0);
        }
    }

    short* Cnat = (z == 0) ? qh : kh;
#pragma unroll
    for (int nf = 0; nf < 2; ++nf) {
        const int n = n_base + nf * 16 + lr;
        const float bv = bias[n];
        const int mrow = m_base + lq * 4;
#pragma unroll
        for (int r = 0; r < 4; ++r) {
            const float val = acc[nf][r] + bv;
            const int m = mrow + r;
            if (z < 2) {
                Cnat[(size_t)m * 512 + n] = f2bf(val);
            } else {
                const int bb = m >> 10, l = m & 1023;
                vht[((size_t)bb * 512 + n) * 1024 + l] = f2bf(val);
            }
        }
    }
}

// ---------------------------------------------------------------------------
// FC GEMM: C[m,n] = sum_k pv[m,k]*Wtfc[n,k] + fc_b[n], fp32 out.
// Same 32x32 tile geometry as proj_gemm. grid (16, 64) -> 8 waves/CU.
// ---------------------------------------------------------------------------
__global__ __launch_bounds__(128) void fc_gemm_kernel(
    const short* __restrict__ A, const short* __restrict__ Bt,
    const float* __restrict__ bias, float* __restrict__ Cout)
{
    const int w = threadIdx.x >> 6, lane = threadIdx.x & 63;
    const int lr = lane & 15, lq = lane >> 4;
    const int m_base = blockIdx.y * 32 + w * 16;
    const int n_base = blockIdx.x * 32;

    f4 acc[2];
    const f4 zero = {0.f, 0.f, 0.f, 0.f};
    acc[0] = zero; acc[1] = zero;

    for (int k0 = 0; k0 < 512; k0 += 32) {
        bf8 a = *(const bf8*)(A + (size_t)(m_base + lr) * 512 + k0 + lq * 8);
#pragma unroll
        for (int nf = 0; nf < 2; ++nf) {
            bf8 b = *(const bf8*)(Bt + (size_t)(n_base + nf * 16 + lr) * 512 + k0 + lq * 8);
            acc[nf] = __builtin_amdgcn_mfma_f32_16x16x32_bf16(a, b, acc[nf], 0, 0, 0);
        }
    }

#pragma unroll
    for (int nf = 0; nf < 2; ++nf) {
        const int n = n_base + nf * 16 + lr;
        const float bv = bias[n];
        const int mrow = m_base + lq * 4;
#pragma unroll
        for (int r = 0; r < 4; ++r)
            Cout[(size_t)(mrow + r) * 512 + n] = acc[nf][r] + bv;
    }
}

// ---------------------------------------------------------------------------
// Scores GEMM: per z=h*2+b, S[l,m] = sum_d qh[b,l,h*64+d]*kh[b,m,h*64+d]
// ---------------------------------------------------------------------------
__global__ __launch_bounds__(256) void scores_mfma_kernel(
    const short* __restrict__ qh, const short* __restrict__ kh,
    float* __restrict__ sc)
{
    const int z = blockIdx.z, h = z >> 1, b = z & 1;
    const int w = threadIdx.x >> 6, lane = threadIdx.x & 63;
    const int wr = w >> 1, wc = w & 1;
    const int lr = lane & 15, lq = lane >> 4;
    const int l0 = blockIdx.y * 128 + wr * 64;
    const int m0 = blockIdx.x * 128 + wc * 64;
    const int colb = h * 64 + lq * 8;
    const size_t base = (size_t)b * L_SEQ * DMODEL;

    bf8 afr[4][2], bfr[4][2];
#pragma unroll
    for (int i = 0; i < 4; ++i)
#pragma unroll
        for (int kk = 0; kk < 2; ++kk) {
            afr[i][kk] = *(const bf8*)(qh + base + (size_t)(l0 + i * 16 + lr) * 512 + colb + kk * 32);
            bfr[i][kk] = *(const bf8*)(kh + base + (size_t)(m0 + i * 16 + lr) * 512 + colb + kk * 32);
        }

    f4 acc[4][4];
    const f4 zero = {0.f, 0.f, 0.f, 0.f};
#pragma unroll
    for (int mt = 0; mt < 4; ++mt)
#pragma unroll
        for (int nt = 0; nt < 4; ++nt) acc[mt][nt] = zero;

#pragma unroll
    for (int kk = 0; kk < 2; ++kk)
#pragma unroll
        for (int mt = 0; mt < 4; ++mt)
#pragma unroll
            for (int nt = 0; nt < 4; ++nt)
                acc[mt][nt] = __builtin_amdgcn_mfma_f32_16x16x32_bf16(
                    afr[mt][kk], bfr[nt][kk], acc[mt][nt], 0, 0, 0);

    float* out = sc + (size_t)z * L_SEQ * L_SEQ;
#pragma unroll
    for (int mt = 0; mt < 4; ++mt)
#pragma unroll
        for (int nt = 0; nt < 4; ++nt)
#pragma unroll
            for (int r = 0; r < 4; ++r)
                out[(size_t)(l0 + mt * 16 + lq * 4 + r) * 1024 + m0 + nt * 16 + lr] = acc[mt][nt][r];
}

// ---------------------------------------------------------------------------
// bias + mask + softmax, one block per (b,l), all 8 heads; in-place on attn.
// Row data loads issued BEFORE emb staging so their latency hides under it.
// ---------------------------------------------------------------------------
__global__ __launch_bounds__(256) void bias_softmax_kernel(
    float* __restrict__ attn,
    const int* __restrict__ mask,
    const int* __restrict__ tf1, const int* __restrict__ tf2,
    const int* __restrict__ tf3, const int* __restrict__ tf4,
    const int* __restrict__ tf5,
    const float* __restrict__ emb1, const float* __restrict__ emb2,
    const float* __restrict__ emb3, const float* __restrict__ emb4,
    const float* __restrict__ emb5)
{
    const int l = blockIdx.x, b = blockIdx.y, t = threadIdx.x;
    __shared__ float embs[5][NHEAD][64];
    __shared__ float redmx[4][NHEAD];
    __shared__ float redsm[4][NHEAD];

    // issue row-data loads first (latency hides under emb staging + barrier)
    const size_t rowbase = ((size_t)(b * L_SEQ + l)) * L_SEQ + (size_t)(t * 4);
    const int4 mk  = *(const int4*)(mask + rowbase);
    const int4 i1v = *(const int4*)(tf1 + rowbase);
    const int4 i2v = *(const int4*)(tf2 + rowbase);
    const int4 i3v = *(const int4*)(tf3 + rowbase);
    const int4 i4v = *(const int4*)(tf4 + rowbase);
    const int4 i5v = *(const int4*)(tf5 + rowbase);

    f4 av[NHEAD];
#pragma unroll
    for (int h = 0; h < NHEAD; ++h)
        av[h] = *(const f4*)(attn + ((size_t)(h * NB + b) * L_SEQ + l) * L_SEQ + t * 4);

    {
        const float* es[5] = {emb1, emb2, emb3, emb4, emb5};
#pragma unroll
        for (int it = 0; it < 10; ++it) {
            const int i = it * 256 + t;
            const int j = it >> 1;               // = i >> 9
            const int rem = i & 511;
            const int h = rem >> 6, idx = rem & 63;
            embs[j][h][idx] = es[j][idx * NHEAD + h];
        }
    }
    __syncthreads();

    // fold bias + mask + 1/temp into registers, branchless on tf1 sign
#define BIAS_FOLD(MI, I1, I2, I3, I4, I5, MK)                                   \
    {                                                                           \
        const float tfm = ((I1) >= 0) ? 1.0f : 0.0f;                            \
        const int c1 = ((I1) >= 0) ? (I1) : 0;                                  \
        _Pragma("unroll")                                                       \
        for (int h = 0; h < NHEAD; ++h) {                                       \
            const float bsum = embs[0][h][c1] + embs[1][h][I2]                  \
                             + embs[2][h][I3] + embs[3][h][I4]                  \
                             + embs[4][h][I5];                                  \
            av[h][MI] = (MK) ? -INFINITY                                        \
                             : (av[h][MI] + bsum * tfm) * 0.125f;               \
        }                                                                       \
    }

    BIAS_FOLD(0, i1v.x, i2v.x, i3v.x, i4v.x, i5v.x, mk.x)
    BIAS_FOLD(1, i1v.y, i2v.y, i3v.y, i4v.y, i5v.y, mk.y)
    BIAS_FOLD(2, i1v.z, i2v.z, i3v.z, i4v.z, i5v.z, mk.z)
    BIAS_FOLD(3, i1v.w, i2v.w, i3v.w, i4v.w, i5v.w, mk.w)
#undef BIAS_FOLD

    const int wid = t >> 6, lane = t & 63;

    // per-head row max: 4 local -> 64-lane butterfly -> cross-wave via LDS
    float mx[NHEAD];
#pragma unroll
    for (int h = 0; h < NHEAD; ++h)
        mx[h] = fmaxf(fmaxf(av[h][0], av[h][1]), fmaxf(av[h][2], av[h][3]));
#pragma unroll
    for (int h = 0; h < NHEAD; ++h) {
#pragma unroll
        for (int off = 1; off < 64; off <<= 1)
            mx[h] = fmaxf(mx[h], __shfl_xor(mx[h], off));
    }
    if (lane == 0) {
#pragma unroll
        for (int h = 0; h < NHEAD; ++h) redmx[wid][h] = mx[h];
    }
    __syncthreads();
#pragma unroll
    for (int h = 0; h < NHEAD; ++h)
        mx[h] = fmaxf(fmaxf(redmx[0][h], redmx[1][h]),
                      fmaxf(redmx[2][h], redmx[3][h]));

    // exp + per-head sum
    float sm[NHEAD];
#pragma unroll
    for (int h = 0; h < NHEAD; ++h) {
        f4 e;
        e[0] = __expf(av[h][0] - mx[h]);
        e[1] = __expf(av[h][1] - mx[h]);
        e[2] = __expf(av[h][2] - mx[h]);
        e[3] = __expf(av[h][3] - mx[h]);
        av[h] = e;
        sm[h] = (e[0] + e[1]) + (e[2] + e[3]);
    }
#pragma unroll
    for (int h = 0; h < NHEAD; ++h) {
#pragma unroll
        for (int off = 1; off < 64; off <<= 1)
            sm[h] += __shfl_xor(sm[h], off);
    }
    if (lane == 0) {
#pragma unroll
        for (int h = 0; h < NHEAD; ++h) redsm[wid][h] = sm[h];
    }
    __syncthreads();

#pragma unroll
    for (int h = 0; h < NHEAD; ++h) {
        const float tot = (redsm[0][h] + redsm[1][h]) + (redsm[2][h] + redsm[3][h]);
        const float inv = 1.0f / tot;
        f4 o = av[h] * inv;
        *(f4*)(attn + ((size_t)(h * NB + b) * L_SEQ + l) * L_SEQ + t * 4) = o;
    }
}

// ---------------------------------------------------------------------------
// AV GEMM, split-K: per z=h*2+b, pv[b,l,h*64+d] = sum_m attn[z,l,m]*vht[b,h*64+d,m]
// Block = 16 rows x 64 d; each of 4 waves owns a 256-wide K-quarter, then
// cross-wave LDS reduce (wave w finalizes cols w*16..w*16+15).
// grid (64, 16) = 1024 blocks -> 4 blocks/CU, 16 waves/CU.
// ---------------------------------------------------------------------------
__global__ __launch_bounds__(256) void av_mfma_kernel(
    const float* __restrict__ attn, const short* __restrict__ vht,
    short* __restrict__ pv)
{
    const int z = blockIdx.y, h = z >> 1, b = z & 1;
    const int w = threadIdx.x >> 6, lane = threadIdx.x & 63;
    const int lr = lane & 15, lq = lane >> 4;
    const int l0 = blockIdx.x * 16;
    const float* Ab = attn + (size_t)z * L_SEQ * L_SEQ;
    const short* Bb = vht + ((size_t)b * 512 + h * 64) * 1024;

    f4 acc[4];
    const f4 zero = {0.f, 0.f, 0.f, 0.f};
#pragma unroll
    for (int nt = 0; nt < 4; ++nt) acc[nt] = zero;

    const int kbeg = w * 256;
    for (int k0 = kbeg; k0 < kbeg + 256; k0 += 32) {
        const float* p = Ab + (size_t)(l0 + lr) * 1024 + k0 + lq * 8;
        float4 f0 = *(const float4*)p;
        float4 f1 = *(const float4*)(p + 4);
        bf8 a;
        a[0] = f2bf(f0.x); a[1] = f2bf(f0.y); a[2] = f2bf(f0.z); a[3] = f2bf(f0.w);
        a[4] = f2bf(f1.x); a[5] = f2bf(f1.y); a[6] = f2bf(f1.z); a[7] = f2bf(f1.w);
#pragma unroll
        for (int nt = 0; nt < 4; ++nt) {
            bf8 bv = *(const bf8*)(Bb + (size_t)(nt * 16 + lr) * 1024 + k0 + lq * 8);
            acc[nt] = __builtin_amdgcn_mfma_f32_16x16x32_bf16(a, bv, acc[nt], 0, 0, 0);
        }
    }

    // cross-wave reduce: red[wave][nt][row][col], padded to 17 for bank spread
    __shared__ float red[4][4][16][17];
#pragma unroll
    for (int nt = 0; nt < 4; ++nt)
#pragma unroll
        for (int r = 0; r < 4; ++r)
            red[w][nt][lq * 4 + r][lr] = acc[nt][r];
    __syncthreads();

    // wave w finalizes n-frag nt == w
    f4 sum = zero;
#pragma unroll
    for (int j = 0; j < 4; ++j)
#pragma unroll
        for (int r = 0; r < 4; ++r)
            sum[r] += red[j][w][lq * 4 + r][lr];

#pragma unroll
    for (int r = 0; r < 4; ++r)
        pv[(size_t)(b * L_SEQ + l0 + lq * 4 + r) * 512 + h * 64 + w * 16 + lr] = f2bf(sum[r]);
}

// ---------------------------------------------------------------------------
// residual add + LayerNorm, one block per row
// ---------------------------------------------------------------------------
__global__ __launch_bounds__(256) void ln_kernel(
    const float* __restrict__ x, const float* __restrict__ res,
    const float* __restrict__ g, const float* __restrict__ bvec,
    float* __restrict__ out)
{
    const int row = blockIdx.x;
    const int t = threadIdx.x;
    float2 xv = ((const float2*)(x + (size_t)row * DMODEL))[t];
    float2 rv = ((const float2*)(res + (size_t)row * DMODEL))[t];
    const float a = xv.x + rv.x;
    const float c = xv.y + rv.y;
    float s = a + c, sq = a * a + c * c;
#pragma unroll
    for (int off = 32; off; off >>= 1) {
        s  += __shfl_down(s, off);
        sq += __shfl_down(sq, off);
    }
    __shared__ float ssum[4], ssq[4];
    __shared__ float smu, srs;
    const int wid = t >> 6, lane = t & 63;
    if (lane == 0) { ssum[wid] = s; ssq[wid] = sq; }
    __syncthreads();
    if (t == 0) {
        float ts = ssum[0] + ssum[1] + ssum[2] + ssum[3];
        float tq = ssq[0] + ssq[1] + ssq[2] + ssq[3];
        float mu = ts * (1.0f / DMODEL);
        float var = tq * (1.0f / DMODEL) - mu * mu;
        smu = mu;
        srs = rsqrtf(var + 1e-5f);
    }
    __syncthreads();
    const float mu = smu, rs = srs;
    float2 gv = ((const float2*)g)[t];
    float2 bv = ((const float2*)bvec)[t];
    float2 o;
    o.x = (a - mu) * rs * gv.x + bv.x;
    o.y = (c - mu) * rs * gv.y + bv.y;
    ((float2*)(out + (size_t)row * DMODEL))[t] = o;
}

extern "C" void kernel_launch(void* const* d_in, const int* in_sizes, int n_in,
                              void* d_out, int out_size, void* d_ws, size_t ws_size,
                              hipStream_t stream)
{
    const float* q    = (const float*)d_in[0];
    const float* k    = (const float*)d_in[1];
    const float* v    = (const float*)d_in[2];
    const int*   mask = (const int*)d_in[3];
    const int*   tf1  = (const int*)d_in[4];
    const int*   tf2  = (const int*)d_in[5];
    const int*   tf3  = (const int*)d_in[6];
    const int*   tf4  = (const int*)d_in[7];
    const int*   tf5  = (const int*)d_in[8];
    const float* w_q  = (const float*)d_in[9];
    const float* b_q  = (const float*)d_in[10];
    const float* w_k  = (const float*)d_in[11];
    const float* b_k  = (const float*)d_in[12];
    const float* w_v  = (const float*)d_in[13];
    const float* b_v  = (const float*)d_in[14];
    const float* emb1 = (const float*)d_in[15];
    const float* emb2 = (const float*)d_in[16];
    const float* emb3 = (const float*)d_in[17];
    const float* emb4 = (const float*)d_in[18];
    const float* emb5 = (const float*)d_in[19];
    const float* fc_w = (const float*)d_in[20];
    const float* fc_b = (const float*)d_in[21];
    const float* ln_g = (const float*)d_in[22];
    const float* ln_b = (const float*)d_in[23];

    float* out  = (float*)d_out;                       // [2048][512]
    float* attn = out + (size_t)NB * L_SEQ * DMODEL;   // [16][1024][1024]

    // ws layout (bytes): total exactly 20 MiB
    char* wsb = (char*)d_ws;
    short* qb   = (short*)(wsb + 0);                    // 2 MiB  [2048][512] bf16
    short* kb   = (short*)(wsb + (2u << 20));           // 2 MiB
    short* vb   = (short*)(wsb + (4u << 20));           // 2 MiB
    short* Wtq  = (short*)(wsb + (6u << 20));           // 0.5 MiB [512n][512k]
    short* Wtk  = (short*)(wsb + (6u << 20) + (512u << 10));
    short* Wtv  = (short*)(wsb + (7u << 20));
    short* Wtfc = (short*)(wsb + (7u << 20) + (512u << 10));
    short* qh   = (short*)(wsb + (8u << 20));           // 2 MiB [2048][512] bf16
    short* kh   = (short*)(wsb + (10u << 20));          // 2 MiB
    short* vht  = (short*)(wsb + (12u << 20));          // 2 MiB [2][512][1024] bf16
    short* pv   = (short*)(wsb + (14u << 20));          // 2 MiB [2048][512] bf16
    float* fco  = (float*)(wsb + (16u << 20));          // 4 MiB [2048][512] fp32

    const int n4 = NB * L_SEQ * DMODEL / 4;             // 262144

    cast3_bf16_kernel<<<dim3(n4 / 256, 3), 256, 0, stream>>>(
        q, k, v, qb, kb, vb, n4);

    transpose_cast_kernel<<<dim3(16, 16, 4), dim3(32, 8), 0, stream>>>(
        w_q, w_k, w_v, fc_w, Wtq, Wtk, Wtv, Wtfc);

    proj_gemm_kernel<<<dim3(16, 64, 3), 128, 0, stream>>>(
        qb, kb, vb, Wtq, Wtk, Wtv, b_q, b_k, b_v, qh, kh, vht);

    scores_mfma_kernel<<<dim3(8, 8, 16), 256, 0, stream>>>(qh, kh, attn);

    bias_softmax_kernel<<<dim3(L_SEQ, NB), 256, 0, stream>>>(
        attn, mask, tf1, tf2, tf3, tf4, tf5, emb1, emb2, emb3, emb4, emb5);

    av_mfma_kernel<<<dim3(64, 16), 256, 0, stream>>>(attn, vht, pv);

    fc_gemm_kernel<<<dim3(16, 64), 128, 0, stream>>>(pv, Wtfc, fc_b, fco);

    ln_kernel<<<NB * L_SEQ, 256, 0, stream>>>(fco, q, ln_g, ln_b, out);
}